// Round 8
// baseline (38.940 us; speedup 1.0000x reference)
//
#include <hip/hip_runtime.h>
#include <math.h>

#define NP   512
#define NT   1024
#define NS   25
#define NPS  (NP*NS)            // 12800
#define MASKN (NP*NT*NS)        // 13107200

// ---- f64 region (double offsets) ----
#define DSA_OFF  0              // dsA [NPS][4]
#define PD_OFF   51200          // pd  [NP][4]
#define NX_OFF   53248
#define NY_OFF   54272
#define NZ_OFF   55296
#define KK_OFF   56320
#define W_OFF    57344          // W64 [NT][10] sign-folded
#define EMPTY_OFF ((size_t)67584 * 8)      // u32[512]
// ---- f32 shadow region (float offsets from F32 base) ----
#define F32_BYTE_OFF (EMPTY_OFF + 2048)
#define FD_OFF   0              // d32  [NPS][4]
#define FPD_OFF  51200          // pd32 [NP][4]
#define FNX_OFF  53248
#define FNY_OFF  54272
#define FNZ_OFF  55296
#define FKK_OFF  56320
#define FW_OFF   57344          // W32 [NT][12], rows prescaled to sum|w|=1

#define CEPS 7.6293945e-06f     // 64 * 2^-23

__device__ __forceinline__ double sgn(double x) {
    return (x > 0.0) ? 1.0 : ((x < 0.0) ? -1.0 : 0.0);
}

// Fused prep: blocks 0..49 rays, 50..53 triangle tables, 54 scatter+emptyMask.
__global__ void prep_all(const float* __restrict__ p,
                         const float* __restrict__ l,
                         const float* __restrict__ hemi,
                         const float* __restrict__ V,
                         const int* __restrict__ indices,
                         const int* __restrict__ pointindex,
                         const float* __restrict__ COL,
                         const float* __restrict__ OPA,
                         double* __restrict__ ws,
                         unsigned* __restrict__ emptyMask,
                         float* __restrict__ out) {
    const int b = blockIdx.x, t = threadIdx.x;
    float* __restrict__ f32w = (float*)((char*)ws + F32_BYTE_OFF);
    if (b < 50) {
        int idx = b * 256 + t;                 // < 12800 exactly
        int pi = idx / NS, si = idx % NS;
        double px = p[pi*3+0], py = p[pi*3+1], pz = p[pi*3+2];
        double lx = l[0], ly = l[1], lz = l[2];
        double ux = lx - px, uy = ly - py, uz = lz - pz;
        double nrm = sqrt(ux*ux + uy*uy + uz*uz);
        ux /= nrm; uy /= nrm; uz /= nrm;
        double c = -uy;
        double wx = -uz, wz = ux;              // w = cross((0,-1,0), u_hat), wy=0
        double m01 = -wz, m10 = wz, m12 = -wx, m21 = wx;
        double q00 = m01*m10;
        double q02 = m01*m12;
        double q11 = m10*m01 + m12*m21;
        double q20 = m21*m10;
        double q22 = m21*m12;
        double ic = 1.0 + c;
        double r00 = 1.0 + q00/ic, r01 = m01,            r02 = q02/ic;
        double r10 = m10,          r11 = 1.0 + q11/ic,   r12 = m12;
        double r20 = q20/ic,       r21 = m21,            r22 = 1.0 + q22/ic;
        double hx = hemi[si*3+0], hy = hemi[si*3+1], hz = hemi[si*3+2];
        double dx = r00*hx + r01*hy + r02*hz + lx - px;
        double dy = r10*hx + r11*hy + r12*hz + ly - py;
        double dz = r20*hx + r21*hy + r22*hz + lz - pz;
        double* dsA = ws + DSA_OFF;
        dsA[idx*4+0] = dx;
        dsA[idx*4+1] = dy;
        dsA[idx*4+2] = dz;
        dsA[idx*4+3] = 0.0;
        *(float4*)(f32w + FD_OFF + idx*4) =
            make_float4((float)dx, (float)dy, (float)dz, 0.0f);
    } else if (b < 54) {
        int n = (b - 50) * 256 + t;            // < 1024 exactly
        const float* v = V + n*12;
        double a0=v[0], a1=v[1], a2=v[2];
        double b0=v[3], b1=v[4], b2=v[5];
        double c0=v[6], c1=v[7], c2=v[8];
        double v3x=v[9], v3y=v[10], v3z=v[11];
        double e1x=b0-a0, e1y=b1-a1, e1z=b2-a2;
        double e2x=c0-a0, e2y=c1-a1, e2z=c2-a2;
        double cx = e1y*e2z - e1z*e2y;
        double cy = e1z*e2x - e1x*e2z;
        double cz = e1x*e2y - e1y*e2x;
        double nn = sqrt(cx*cx + cy*cy + cz*cz);
        double nx = cx/nn, ny = cy/nn, nz = cz/nn;
        double kk = -(nx*v3x + ny*v3y + nz*v3z);
        double Bv = a0*b2 - a2*b0;
        double Dv = a0*b1 - a1*b0;
        double Ec = a0*c2 - a2*c0;
        double G2 = a1*c0 - a0*c1;
        double Fc = Bv*G2;
        double gd = Dv*(Ec*Dv + Fc);
        double gq = Dv*gd;
        double dq = Dv*c0;
        double aq = a0*gq;
        double WGr0 = a1*Bv - a2*Dv, WGr1 = -(a0*Bv), WGr2 = a0*Dv;
        double dg = Dv*G2;
        double WBr0 = -(a1*gd) + dg*WGr0;
        double WBr1 =  a0*gd  + dg*WGr1;
        double WBr2 =            dg*WGr2;
        double dd = Dv*dq;
        double WAr0 = gq - b0*WBr0 - dd*WGr0;
        double WAr1 =    - b0*WBr1 - dd*WGr1;
        double WAr2 =    - b0*WBr2 - dd*WGr2;
        double sg = sgn(Dv*gd), sb = sgn(gq), sa = sgn(aq);
        ws[NX_OFF + n] = nx;
        ws[NY_OFF + n] = ny;
        ws[NZ_OFF + n] = nz;
        ws[KK_OFF + n] = kk;
        double g0 = WGr0*sg, g1 = WGr1*sg, g2 = WGr2*sg;
        double bb0 = WBr0*sb, bb1 = WBr1*sb, bb2 = WBr2*sb;
        double aa0 = WAr0*sa, aa1 = WAr1*sa, aa2 = WAr2*sa;
        double* W = ws + W_OFF + n*10;
        W[0]=g0; W[1]=g1; W[2]=g2;
        W[3]=bb0; W[4]=bb1; W[5]=bb2;
        W[6]=aa0; W[7]=aa1; W[8]=aa2;
        W[9]=0.0;
        f32w[FNX_OFF+n]=(float)nx; f32w[FNY_OFF+n]=(float)ny;
        f32w[FNZ_OFF+n]=(float)nz; f32w[FKK_OFF+n]=(float)kk;
        double wsg = fabs(g0)+fabs(g1)+fabs(g2);
        double wsb = fabs(bb0)+fabs(bb1)+fabs(bb2);
        double wsa = fabs(aa0)+fabs(aa1)+fabs(aa2);
        double ig = wsg>0.0 ? 1.0/wsg : 0.0;
        double ib = wsb>0.0 ? 1.0/wsb : 0.0;
        double ia = wsa>0.0 ? 1.0/wsa : 0.0;
        float* fw = f32w + FW_OFF + n*12;
        fw[0]=(float)(g0*ig);  fw[1]=(float)(g1*ig);  fw[2]=(float)(g2*ig);
        fw[3]=(float)(bb0*ib); fw[4]=(float)(bb1*ib); fw[5]=(float)(bb2*ib);
        fw[6]=(float)(aa0*ia); fw[7]=(float)(aa1*ia); fw[8]=(float)(aa2*ia);
        fw[9]=0.0f; fw[10]=0.0f; fw[11]=0.0f;
    } else {
        emptyMask[t] = 0u;
        emptyMask[t + 256] = 0u;
        __syncthreads();
        for (int i = t; i < NP; i += 256) {
            int pidx = pointindex[i];
            int local = pidx & (NP - 1);
            int surf = indices[pidx*2 + 0];
            int mat  = indices[pidx*2 + 1];
            atomicOr(&emptyMask[local], 1u << surf);
            float* colOut = out + MASKN;
            float* opaOut = out + MASKN + 3*NP;
            float* refOut = out + MASKN + 4*NP;
            colOut[i*3+0] = COL[(surf*8+mat)*3+0];
            colOut[i*3+1] = COL[(surf*8+mat)*3+1];
            colOut[i*3+2] = COL[(surf*8+mat)*3+2];
            float o = OPA[surf*8+mat];
            opaOut[i] = fminf(fmaxf(o, 0.0f), 1.0f);
            refOut[i*3+0] = (float)((double)l[0] - (double)p[i*3+0]);
            refOut[i*3+1] = (float)((double)l[1] - (double)p[i*3+1]);
            refOut[i*3+2] = (float)((double)l[2] - (double)p[i*3+2]);
            double* pd = ws + PD_OFF;
            pd[i*4+0] = (double)p[i*3+0];
            pd[i*4+1] = (double)p[i*3+1];
            pd[i*4+2] = (double)p[i*3+2];
            pd[i*4+3] = 0.0;
            *(float4*)(f32w + FPD_OFF + i*4) =
                make_float4(p[i*3+0], p[i*3+1], p[i*3+2], 0.0f);
        }
    }
}

// Exact f64 recheck (sign tests only; empty handled by caller). Rare.
__device__ __noinline__ unsigned recheck64(const double* __restrict__ ws,
        unsigned ps, unsigned pp, unsigned n, unsigned nn, unsigned ss) {
    const double* s = ws + DSA_OFF + ps*4u;
    const double* o = ws + PD_OFF + pp*4u;
    double nx = ws[NX_OFF+n], ny = ws[NY_OFF+n], nz = ws[NZ_OFF+n];
    double kk = ws[KK_OFF+n];
    double vd = fma(s[2], nz, fma(s[1], ny, s[0]*nx));
    double tt = fma(o[2], nz, fma(o[1], ny, fma(o[0], nx, kk)));
    double e1 = fma(1e-4, vd, -tt);
    double e2 = vd + tt;
    const double* d = ws + DSA_OFF + (pp*25u + ss)*4u;
    double R0 = fma(-tt, d[0], vd*o[0]);
    double R1 = fma(-tt, d[1], vd*o[1]);
    double R2 = fma(-tt, d[2], vd*o[2]);
    const double* w = ws + W_OFF + nn*10u;
    double dG = fma(R2, w[2], fma(R1, w[1], R0*w[0]));
    double dB = fma(R2, w[5], fma(R1, w[4], R0*w[3]));
    double dA = fma(R2, w[8], fma(R1, w[7], R0*w[6]));
    int hv = __double2hiint(vd);
    int m = (__double2hiint(e1)^hv) | (__double2hiint(e2)^hv)
          | (__double2hiint(dG)^hv) | (__double2hiint(dB)^hv)
          | (__double2hiint(dA)^hv);
    return (m >= 0) ? 1u : 0u;
}

// (pp,nn)-organized main kernel. Block = half of one point pp (512 nn),
// thread owns 2 nn x 25 ss = 50 elements. Per element:
//   w row: registers (loaded once per nn from global, L2-hot)
//   nrm/kk: LDS SoA, lane-stride 25 (odd) -> conflict-free
//   d[ss]: wave-uniform LDS float4 broadcast
//   s[ps]: <=2 values per nn, hoisted + per-iter select
// Results -> 25-bit masks -> LDS -> phase-2 coalesced float2 expansion.
__global__ __launch_bounds__(256, 4) void diffuse_main(
        const double* __restrict__ ws,
        const unsigned* __restrict__ emptyMask,
        float* __restrict__ out) {
    __shared__ __align__(16) float snx[NT], sny[NT], snz[NT], skk[NT];
    __shared__ float4 sdr[NS];
    __shared__ unsigned sbits[512];

    const float* __restrict__ f32 = (const float*)((const char*)ws + F32_BYTE_OFF);
    const unsigned pp = blockIdx.x >> 1;
    const unsigned half = blockIdx.x & 1u;
    const unsigned tid = threadIdx.x;
    const unsigned nnA = half*512u + tid;
    const unsigned nnB = nnA + 256u;

    // early global loads (independent of LDS)
    const float4 wA0 = *(const float4*)(f32 + FW_OFF + nnA*12u);
    const float4 wA1 = *(const float4*)(f32 + FW_OFF + nnA*12u + 4u);
    const float4 wA2 = *(const float4*)(f32 + FW_OFF + nnA*12u + 8u);
    const float4 wB0 = *(const float4*)(f32 + FW_OFF + nnB*12u);
    const float4 wB1 = *(const float4*)(f32 + FW_OFF + nnB*12u + 4u);
    const float4 wB2 = *(const float4*)(f32 + FW_OFF + nnB*12u + 8u);
    const float ox = f32[FPD_OFF + pp*4u + 0];
    const float oy = f32[FPD_OFF + pp*4u + 1];
    const float oz = f32[FPD_OFF + pp*4u + 2];
    const unsigned em = emptyMask[pp];

    // stage nrm SoA (16 KB) + ray d-vectors
    {
        const unsigned i4 = tid * 4u;
        *(float4*)&snx[i4] = *(const float4*)(f32 + FNX_OFF + i4);
        *(float4*)&sny[i4] = *(const float4*)(f32 + FNY_OFF + i4);
        *(float4*)&snz[i4] = *(const float4*)(f32 + FNZ_OFF + i4);
        *(float4*)&skk[i4] = *(const float4*)(f32 + FKK_OFF + i4);
    }
    if (tid < 25u) {
        float4 dr = *(const float4*)(f32 + FD_OFF + (pp*25u + tid)*4u);
        dr.w = fmaxf(fabsf(dr.x), fmaxf(fabsf(dr.y), fabsf(dr.z)));
        sdr[tid] = dr;
    }
    __syncthreads();

    const float O1u = fabsf(ox) + fabsf(oy) + fabsf(oz);

    #pragma unroll
    for (int h = 0; h < 2; ++h) {
        const unsigned nn = h ? nnB : nnA;
        const float4 w0 = h ? wB0 : wA0;
        const float4 w1 = h ? wB1 : wA1;
        const float4 w2 = h ? wB2 : wA2;
        const unsigned m0  = nn * 25u;
        const unsigned n0  = m0 & 1023u;
        const unsigned ps0 = m0 >> 10;
        const unsigned idx1 = (m0 + 24u) >> 10;
        const unsigned ssX = ((ps0 + 1u) << 10) - m0;   // >=25 if no crossing
        const float4 s0v = sdr[ps0];
        const float4 s1v = sdr[idx1];
        const float S10 = fabsf(s0v.x) + fabsf(s0v.y) + fabsf(s0v.z);
        const float S11 = fabsf(s1v.x) + fabsf(s1v.y) + fabsf(s1v.z);

        unsigned acc = 0u, flg = 0u;
        #pragma unroll 5
        for (unsigned ss = 0u; ss < 25u; ++ss) {
            const bool cr = (ss >= ssX);
            const float sx = cr ? s1v.x : s0v.x;
            const float sy = cr ? s1v.y : s0v.y;
            const float sz = cr ? s1v.z : s0v.z;
            const float S1u = cr ? S11 : S10;
            const unsigned n = n0 + ss - (cr ? 1024u : 0u);
            const float nx = snx[n], ny = sny[n], nz = snz[n], kk = skk[n];

            const float vd = fmaf(sz, nz, fmaf(sy, ny, sx*nx));
            const float tt = fmaf(oz, nz, fmaf(oy, ny, fmaf(ox, nx, kk)));
            const float e1 = fmaf(1e-4f, vd, -tt);     // t > -1e-4
            const float e2 = vd + tt;                  // t < 1

            const float4 d4 = sdr[ss];                 // uniform -> broadcast
            const float R0 = fmaf(-tt, d4.x, vd*ox);
            const float R1 = fmaf(-tt, d4.y, vd*oy);
            const float R2 = fmaf(-tt, d4.z, vd*oz);

            const float dG = fmaf(R2, w0.z, fmaf(R1, w0.y, R0*w0.x));
            const float dB = fmaf(R2, w1.y, fmaf(R1, w1.x, R0*w0.w));
            const float dA = fmaf(R2, w2.x, fmaf(R1, w1.w, R0*w1.z));

            const int hv = __float_as_int(vd);
            const int msk = (__float_as_int(e1)^hv) | (__float_as_int(e2)^hv)
                          | (__float_as_int(dG)^hv) | (__float_as_int(dB)^hv)
                          | (__float_as_int(dA)^hv);
            acc |= ((unsigned)(msk >= 0)) << ss;

            // rounding-error guards (same semantics as round 7)
            const float akk = fabsf(kk);
            const float Ee  = CEPS * (S1u + O1u + akk);
            const float Mtt = O1u + akk;
            const float MR  = fmaf(Mtt, d4.w, S1u * O1u);
            const float Edx = CEPS * MR;
            const float mind = fminf(fabsf(dG), fminf(fabsf(dB), fabsf(dA)));
            const bool flag = (fabsf(vd) < CEPS*S1u) | (fabsf(e1) < Ee)
                            | (fabsf(e2) < Ee) | (mind < Edx);
            flg |= ((unsigned)flag) << ss;
        }
        if (__builtin_expect(flg != 0u, 0)) {
            unsigned f2 = flg;
            while (f2) {
                const unsigned ss = (unsigned)__ffs(f2) - 1u;
                f2 &= f2 - 1u;
                const bool cr = (ss >= ssX);
                const unsigned n = n0 + ss - (cr ? 1024u : 0u);
                const unsigned ps = pp*25u + ps0 + (cr ? 1u : 0u);
                const unsigned bit = recheck64(ws, ps, pp, n, nn, ss);
                acc = (acc & ~(1u << ss)) | (bit << ss);
            }
        }
        if ((nn < 8u) && ((em >> nn) & 1u)) acc = 0u;   // empty row
        sbits[h*256u + tid] = acc;
    }
    __syncthreads();

    // phase 2: expand 512 x 25 bits -> 12800 coalesced floats
    const unsigned obase = pp*25600u + half*12800u;
    #pragma unroll 5
    for (unsigned it = 0u; it < 25u; ++it) {
        const unsigned j = (it*256u + tid) * 2u;
        const unsigned nn1 = j / 25u;
        const unsigned ss1 = j - nn1*25u;
        const unsigned j2 = j + 1u;
        const unsigned nn2 = j2 / 25u;
        const unsigned ss2 = j2 - nn2*25u;
        const float r0 = ((sbits[nn1] >> ss1) & 1u) ? 1.0f : 0.0f;
        const float r1 = ((sbits[nn2] >> ss2) & 1u) ? 1.0f : 0.0f;
        *(float2*)(out + obase + j) = make_float2(r0, r1);
    }
}

extern "C" void kernel_launch(void* const* d_in, const int* in_sizes, int n_in,
                              void* d_out, int out_size, void* d_ws, size_t ws_size,
                              hipStream_t stream) {
    const float* V         = (const float*)d_in[0];
    const int*   indices   = (const int*)  d_in[1];
    const int*   pointindex= (const int*)  d_in[2];
    const float* COL       = (const float*)d_in[3];
    const float* OPA       = (const float*)d_in[4];
    const float* p         = (const float*)d_in[5];
    const float* l         = (const float*)d_in[6];
    // d_in[7] = normals (unused), d_in[8] = it (unused)
    const float* hemi      = (const float*)d_in[9];

    float* out = (float*)d_out;
    double* ws = (double*)d_ws;
    unsigned* emptyMask = (unsigned*)((char*)d_ws + EMPTY_OFF);

    prep_all<<<55, 256, 0, stream>>>(p, l, hemi, V, indices, pointindex,
                                     COL, OPA, ws, emptyMask, out);
    diffuse_main<<<NP*2, 256, 0, stream>>>(ws, emptyMask, out);
}

// Round 9
// 37.301 us; speedup vs baseline: 1.0439x; 1.0439x over previous
//
#include <hip/hip_runtime.h>
#include <math.h>

#define NP   512
#define NT   1024
#define NS   25
#define NPS  (NP*NS)            // 12800
#define MASKN (NP*NT*NS)        // 13107200

// ---- f64 region (double offsets) ----
#define DSA_OFF  0              // dsA [NPS][4]
#define PD_OFF   51200          // pd  [NP][4]
#define NX_OFF   53248
#define NY_OFF   54272
#define NZ_OFF   55296
#define KK_OFF   56320
#define W_OFF    57344          // W64 [NT][10] sign-folded
#define EMPTY_OFF ((size_t)67584 * 8)      // u32[512]
// ---- f32 shadow region (float offsets from F32 base) ----
#define F32_BYTE_OFF (EMPTY_OFF + 2048)
#define FD_OFF   0              // d32  [NPS][4]
#define FPD_OFF  51200          // pd32 [NP][4]
#define FNX_OFF  53248
#define FNY_OFF  54272
#define FNZ_OFF  55296
#define FKK_OFF  56320
#define FW_OFF   57344          // W32 [NT][12], rows prescaled to sum|w|=1

#define CEPS 7.6293945e-06f     // 64 * 2^-23

__device__ __forceinline__ double sgn(double x) {
    return (x > 0.0) ? 1.0 : ((x < 0.0) ? -1.0 : 0.0);
}

// Fused prep: blocks 0..49 rays, 50..53 triangle tables, 54 scatter+emptyMask.
__global__ void prep_all(const float* __restrict__ p,
                         const float* __restrict__ l,
                         const float* __restrict__ hemi,
                         const float* __restrict__ V,
                         const int* __restrict__ indices,
                         const int* __restrict__ pointindex,
                         const float* __restrict__ COL,
                         const float* __restrict__ OPA,
                         double* __restrict__ ws,
                         unsigned* __restrict__ emptyMask,
                         float* __restrict__ out) {
    const int b = blockIdx.x, t = threadIdx.x;
    float* __restrict__ f32w = (float*)((char*)ws + F32_BYTE_OFF);
    if (b < 50) {
        int idx = b * 256 + t;                 // < 12800 exactly
        int pi = idx / NS, si = idx % NS;
        double px = p[pi*3+0], py = p[pi*3+1], pz = p[pi*3+2];
        double lx = l[0], ly = l[1], lz = l[2];
        double ux = lx - px, uy = ly - py, uz = lz - pz;
        double nrm = sqrt(ux*ux + uy*uy + uz*uz);
        ux /= nrm; uy /= nrm; uz /= nrm;
        double c = -uy;
        double wx = -uz, wz = ux;              // w = cross((0,-1,0), u_hat), wy=0
        double m01 = -wz, m10 = wz, m12 = -wx, m21 = wx;
        double q00 = m01*m10;
        double q02 = m01*m12;
        double q11 = m10*m01 + m12*m21;
        double q20 = m21*m10;
        double q22 = m21*m12;
        double ic = 1.0 + c;
        double r00 = 1.0 + q00/ic, r01 = m01,            r02 = q02/ic;
        double r10 = m10,          r11 = 1.0 + q11/ic,   r12 = m12;
        double r20 = q20/ic,       r21 = m21,            r22 = 1.0 + q22/ic;
        double hx = hemi[si*3+0], hy = hemi[si*3+1], hz = hemi[si*3+2];
        double dx = r00*hx + r01*hy + r02*hz + lx - px;
        double dy = r10*hx + r11*hy + r12*hz + ly - py;
        double dz = r20*hx + r21*hy + r22*hz + lz - pz;
        double* dsA = ws + DSA_OFF;
        dsA[idx*4+0] = dx;
        dsA[idx*4+1] = dy;
        dsA[idx*4+2] = dz;
        dsA[idx*4+3] = 0.0;
        *(float4*)(f32w + FD_OFF + idx*4) =
            make_float4((float)dx, (float)dy, (float)dz, 0.0f);
    } else if (b < 54) {
        int n = (b - 50) * 256 + t;            // < 1024 exactly
        const float* v = V + n*12;
        double a0=v[0], a1=v[1], a2=v[2];
        double b0=v[3], b1=v[4], b2=v[5];
        double c0=v[6], c1=v[7], c2=v[8];
        double v3x=v[9], v3y=v[10], v3z=v[11];
        double e1x=b0-a0, e1y=b1-a1, e1z=b2-a2;
        double e2x=c0-a0, e2y=c1-a1, e2z=c2-a2;
        double cx = e1y*e2z - e1z*e2y;
        double cy = e1z*e2x - e1x*e2z;
        double cz = e1x*e2y - e1y*e2x;
        double nn = sqrt(cx*cx + cy*cy + cz*cz);
        double nx = cx/nn, ny = cy/nn, nz = cz/nn;
        double kk = -(nx*v3x + ny*v3y + nz*v3z);
        double Bv = a0*b2 - a2*b0;
        double Dv = a0*b1 - a1*b0;
        double Ec = a0*c2 - a2*c0;
        double G2 = a1*c0 - a0*c1;
        double Fc = Bv*G2;
        double gd = Dv*(Ec*Dv + Fc);
        double gq = Dv*gd;
        double dq = Dv*c0;
        double aq = a0*gq;
        double WGr0 = a1*Bv - a2*Dv, WGr1 = -(a0*Bv), WGr2 = a0*Dv;
        double dg = Dv*G2;
        double WBr0 = -(a1*gd) + dg*WGr0;
        double WBr1 =  a0*gd  + dg*WGr1;
        double WBr2 =            dg*WGr2;
        double dd = Dv*dq;
        double WAr0 = gq - b0*WBr0 - dd*WGr0;
        double WAr1 =    - b0*WBr1 - dd*WGr1;
        double WAr2 =    - b0*WBr2 - dd*WGr2;
        double sg = sgn(Dv*gd), sb = sgn(gq), sa = sgn(aq);
        ws[NX_OFF + n] = nx;
        ws[NY_OFF + n] = ny;
        ws[NZ_OFF + n] = nz;
        ws[KK_OFF + n] = kk;
        double g0 = WGr0*sg, g1 = WGr1*sg, g2 = WGr2*sg;
        double bb0 = WBr0*sb, bb1 = WBr1*sb, bb2 = WBr2*sb;
        double aa0 = WAr0*sa, aa1 = WAr1*sa, aa2 = WAr2*sa;
        double* W = ws + W_OFF + n*10;
        W[0]=g0; W[1]=g1; W[2]=g2;
        W[3]=bb0; W[4]=bb1; W[5]=bb2;
        W[6]=aa0; W[7]=aa1; W[8]=aa2;
        W[9]=0.0;
        f32w[FNX_OFF+n]=(float)nx; f32w[FNY_OFF+n]=(float)ny;
        f32w[FNZ_OFF+n]=(float)nz; f32w[FKK_OFF+n]=(float)kk;
        double wsg = fabs(g0)+fabs(g1)+fabs(g2);
        double wsb = fabs(bb0)+fabs(bb1)+fabs(bb2);
        double wsa = fabs(aa0)+fabs(aa1)+fabs(aa2);
        double ig = wsg>0.0 ? 1.0/wsg : 0.0;
        double ib = wsb>0.0 ? 1.0/wsb : 0.0;
        double ia = wsa>0.0 ? 1.0/wsa : 0.0;
        float* fw = f32w + FW_OFF + n*12;
        fw[0]=(float)(g0*ig);  fw[1]=(float)(g1*ig);  fw[2]=(float)(g2*ig);
        fw[3]=(float)(bb0*ib); fw[4]=(float)(bb1*ib); fw[5]=(float)(bb2*ib);
        fw[6]=(float)(aa0*ia); fw[7]=(float)(aa1*ia); fw[8]=(float)(aa2*ia);
        fw[9]=0.0f; fw[10]=0.0f; fw[11]=0.0f;
    } else {
        emptyMask[t] = 0u;
        emptyMask[t + 256] = 0u;
        __syncthreads();
        for (int i = t; i < NP; i += 256) {
            int pidx = pointindex[i];
            int local = pidx & (NP - 1);
            int surf = indices[pidx*2 + 0];
            int mat  = indices[pidx*2 + 1];
            atomicOr(&emptyMask[local], 1u << surf);
            float* colOut = out + MASKN;
            float* opaOut = out + MASKN + 3*NP;
            float* refOut = out + MASKN + 4*NP;
            colOut[i*3+0] = COL[(surf*8+mat)*3+0];
            colOut[i*3+1] = COL[(surf*8+mat)*3+1];
            colOut[i*3+2] = COL[(surf*8+mat)*3+2];
            float o = OPA[surf*8+mat];
            opaOut[i] = fminf(fmaxf(o, 0.0f), 1.0f);
            refOut[i*3+0] = (float)((double)l[0] - (double)p[i*3+0]);
            refOut[i*3+1] = (float)((double)l[1] - (double)p[i*3+1]);
            refOut[i*3+2] = (float)((double)l[2] - (double)p[i*3+2]);
            double* pd = ws + PD_OFF;
            pd[i*4+0] = (double)p[i*3+0];
            pd[i*4+1] = (double)p[i*3+1];
            pd[i*4+2] = (double)p[i*3+2];
            pd[i*4+3] = 0.0;
            *(float4*)(f32w + FPD_OFF + i*4) =
                make_float4(p[i*3+0], p[i*3+1], p[i*3+2], 0.0f);
        }
    }
}

// Exact f64 recheck (sign tests only; empty handled by caller). Rare.
__device__ __noinline__ unsigned recheck64(const double* __restrict__ ws,
        unsigned ps, unsigned pp, unsigned n, unsigned nn, unsigned ss) {
    const double* s = ws + DSA_OFF + ps*4u;
    const double* o = ws + PD_OFF + pp*4u;
    double nx = ws[NX_OFF+n], ny = ws[NY_OFF+n], nz = ws[NZ_OFF+n];
    double kk = ws[KK_OFF+n];
    double vd = fma(s[2], nz, fma(s[1], ny, s[0]*nx));
    double tt = fma(o[2], nz, fma(o[1], ny, fma(o[0], nx, kk)));
    double e1 = fma(1e-4, vd, -tt);
    double e2 = vd + tt;
    const double* d = ws + DSA_OFF + (pp*25u + ss)*4u;
    double R0 = fma(-tt, d[0], vd*o[0]);
    double R1 = fma(-tt, d[1], vd*o[1]);
    double R2 = fma(-tt, d[2], vd*o[2]);
    const double* w = ws + W_OFF + nn*10u;
    double dG = fma(R2, w[2], fma(R1, w[1], R0*w[0]));
    double dB = fma(R2, w[5], fma(R1, w[4], R0*w[3]));
    double dA = fma(R2, w[8], fma(R1, w[7], R0*w[6]));
    int hv = __double2hiint(vd);
    int m = (__double2hiint(e1)^hv) | (__double2hiint(e2)^hv)
          | (__double2hiint(dG)^hv) | (__double2hiint(dB)^hv)
          | (__double2hiint(dA)^hv);
    return (m >= 0) ? 1u : 0u;
}

// Round 9: nn-organization with fixed execution shape.
// Block = quarter of one point pp (256 nn rows); thread = ONE nn (25 elements).
// Grid 2048 (8 blocks/CU), no occupancy clamp (avoid forced spills).
// Per element: 4 conflict-free LDS b32 (lane stride 25) + 1 broadcast b128;
// w row in 3 float4 registers (coalesced 48B/thread global load, L2-hot).
// Results bit-packed, phase 2 expands to coalesced float2 stores.
__global__ __launch_bounds__(256) void diffuse_main(
        const double* __restrict__ ws,
        const unsigned* __restrict__ emptyMask,
        float* __restrict__ out) {
    __shared__ __align__(16) float snx[NT], sny[NT], snz[NT], skk[NT];
    __shared__ float4 sdr[NS];
    __shared__ unsigned sbits[256];

    const float* __restrict__ f32 = (const float*)((const char*)ws + F32_BYTE_OFF);
    const unsigned pp = blockIdx.x >> 2;
    const unsigned quarter = blockIdx.x & 3u;
    const unsigned tid = threadIdx.x;
    const unsigned nn = quarter*256u + tid;      // output triangle column

    // early global loads (independent of LDS staging)
    const float4 w0 = *(const float4*)(f32 + FW_OFF + nn*12u);
    const float4 w1 = *(const float4*)(f32 + FW_OFF + nn*12u + 4u);
    const float4 w2 = *(const float4*)(f32 + FW_OFF + nn*12u + 8u);
    const float ox = f32[FPD_OFF + pp*4u + 0];
    const float oy = f32[FPD_OFF + pp*4u + 1];
    const float oz = f32[FPD_OFF + pp*4u + 2];
    const unsigned em = emptyMask[pp];

    // stage nrm SoA (16 KB) + ray d-vectors
    {
        const unsigned i4 = tid * 4u;
        *(float4*)&snx[i4] = *(const float4*)(f32 + FNX_OFF + i4);
        *(float4*)&sny[i4] = *(const float4*)(f32 + FNY_OFF + i4);
        *(float4*)&snz[i4] = *(const float4*)(f32 + FNZ_OFF + i4);
        *(float4*)&skk[i4] = *(const float4*)(f32 + FKK_OFF + i4);
    }
    if (tid < 25u) {
        float4 dr = *(const float4*)(f32 + FD_OFF + (pp*25u + tid)*4u);
        dr.w = fmaxf(fabsf(dr.x), fmaxf(fabsf(dr.y), fabsf(dr.z)));
        sdr[tid] = dr;
    }
    __syncthreads();

    const float O1u = fabsf(ox) + fabsf(oy) + fabsf(oz);

    const unsigned local0 = quarter*6400u + tid*25u;   // within-pp flat offset
    const unsigned n0  = local0 & 1023u;
    const unsigned ps0 = local0 >> 10;                 // within-pp ray index
    const unsigned ssX = 1024u - n0;                   // >=25 means no crossing
    const unsigned ps1 = (ssX < 25u) ? (ps0 + 1u) : ps0;
    const float4 s0v = sdr[ps0];
    const float4 s1v = sdr[ps1];
    const float S10 = fabsf(s0v.x) + fabsf(s0v.y) + fabsf(s0v.z);
    const float S11 = fabsf(s1v.x) + fabsf(s1v.y) + fabsf(s1v.z);

    unsigned acc = 0u, flg = 0u;
    #pragma unroll 5
    for (unsigned ss = 0u; ss < 25u; ++ss) {
        const bool cr = (ss >= ssX);
        const float sx = cr ? s1v.x : s0v.x;
        const float sy = cr ? s1v.y : s0v.y;
        const float sz = cr ? s1v.z : s0v.z;
        const float S1u = cr ? S11 : S10;
        const unsigned n = n0 + ss - (cr ? 1024u : 0u);
        const float nx = snx[n], ny = sny[n], nz = snz[n], kk = skk[n];

        const float vd = fmaf(sz, nz, fmaf(sy, ny, sx*nx));
        const float tt = fmaf(oz, nz, fmaf(oy, ny, fmaf(ox, nx, kk)));
        const float e1 = fmaf(1e-4f, vd, -tt);     // t > -1e-4
        const float e2 = vd + tt;                  // t < 1

        const float4 d4 = sdr[ss];                 // uniform -> broadcast
        const float R0 = fmaf(-tt, d4.x, vd*ox);
        const float R1 = fmaf(-tt, d4.y, vd*oy);
        const float R2 = fmaf(-tt, d4.z, vd*oz);

        const float dG = fmaf(R2, w0.z, fmaf(R1, w0.y, R0*w0.x));
        const float dB = fmaf(R2, w1.y, fmaf(R1, w1.x, R0*w0.w));
        const float dA = fmaf(R2, w2.x, fmaf(R1, w1.w, R0*w1.z));

        const int hv = __float_as_int(vd);
        const int msk = (__float_as_int(e1)^hv) | (__float_as_int(e2)^hv)
                      | (__float_as_int(dG)^hv) | (__float_as_int(dB)^hv)
                      | (__float_as_int(dA)^hv);
        acc |= ((unsigned)(msk >= 0)) << ss;

        // rounding-error guards (same semantics as rounds 7-8)
        const float akk = fabsf(kk);
        const float Ee  = CEPS * (S1u + O1u + akk);
        const float Mtt = O1u + akk;
        const float MR  = fmaf(Mtt, d4.w, S1u * O1u);
        const float Edx = CEPS * MR;
        const float mind = fminf(fabsf(dG), fminf(fabsf(dB), fabsf(dA)));
        const bool flag = (fabsf(vd) < CEPS*S1u) | (fabsf(e1) < Ee)
                        | (fabsf(e2) < Ee) | (mind < Edx);
        flg |= ((unsigned)flag) << ss;
    }
    if (__builtin_expect(flg != 0u, 0)) {
        unsigned f2 = flg;
        while (f2) {
            const unsigned ss = (unsigned)__ffs(f2) - 1u;
            f2 &= f2 - 1u;
            const bool cr = (ss >= ssX);
            const unsigned n = n0 + ss - (cr ? 1024u : 0u);
            const unsigned ps = pp*25u + (cr ? ps1 : ps0);
            const unsigned bit = recheck64(ws, ps, pp, n, nn, ss);
            acc = (acc & ~(1u << ss)) | (bit << ss);
        }
    }
    if ((nn < 8u) && ((em >> nn) & 1u)) acc = 0u;   // empty row
    sbits[tid] = acc;
    __syncthreads();

    // phase 2: expand 256 x 25 bits -> 6400 coalesced floats
    const unsigned obase = pp*25600u + quarter*6400u;
    #pragma unroll
    for (unsigned it = 0u; it < 13u; ++it) {
        const unsigned j = (it*256u + tid) * 2u;
        if (j < 6400u) {
            const unsigned nn1 = j / 25u;
            const unsigned ss1 = j - nn1*25u;
            const unsigned j2 = j + 1u;
            const unsigned nn2 = j2 / 25u;
            const unsigned ss2 = j2 - nn2*25u;
            const float r0 = ((sbits[nn1] >> ss1) & 1u) ? 1.0f : 0.0f;
            const float r1 = ((sbits[nn2] >> ss2) & 1u) ? 1.0f : 0.0f;
            *(float2*)(out + obase + j) = make_float2(r0, r1);
        }
    }
}

extern "C" void kernel_launch(void* const* d_in, const int* in_sizes, int n_in,
                              void* d_out, int out_size, void* d_ws, size_t ws_size,
                              hipStream_t stream) {
    const float* V         = (const float*)d_in[0];
    const int*   indices   = (const int*)  d_in[1];
    const int*   pointindex= (const int*)  d_in[2];
    const float* COL       = (const float*)d_in[3];
    const float* OPA       = (const float*)d_in[4];
    const float* p         = (const float*)d_in[5];
    const float* l         = (const float*)d_in[6];
    // d_in[7] = normals (unused), d_in[8] = it (unused)
    const float* hemi      = (const float*)d_in[9];

    float* out = (float*)d_out;
    double* ws = (double*)d_ws;
    unsigned* emptyMask = (unsigned*)((char*)d_ws + EMPTY_OFF);

    prep_all<<<55, 256, 0, stream>>>(p, l, hemi, V, indices, pointindex,
                                     COL, OPA, ws, emptyMask, out);
    diffuse_main<<<NP*4, 256, 0, stream>>>(ws, emptyMask, out);
}

// Round 10
// 36.535 us; speedup vs baseline: 1.0658x; 1.0210x over previous
//
#include <hip/hip_runtime.h>
#include <math.h>

#define NP   512
#define NT   1024
#define NS   25
#define NPS  (NP*NS)            // 12800
#define MASKN (NP*NT*NS)        // 13107200

// ---- f64 region (double offsets) ----
#define DSA_OFF  0              // dsA [NPS][4]
#define PD_OFF   51200          // pd  [NP][4]
#define NX_OFF   53248
#define NY_OFF   54272
#define NZ_OFF   55296
#define KK_OFF   56320
#define W_OFF    57344          // W64 [NT][10] sign-folded
#define EMPTY_OFF ((size_t)67584 * 8)      // u32[512]
// ---- f32 shadow region (float offsets from F32 base) ----
#define F32_BYTE_OFF (EMPTY_OFF + 2048)
#define FD_OFF   0              // d32  [NPS][4]
#define FPD_OFF  51200          // pd32 [NP][4]
#define FNX_OFF  53248
#define FNY_OFF  54272
#define FNZ_OFF  55296
#define FKK_OFF  56320
#define FW_OFF   57344          // W32 [NT][12], rows prescaled to sum|w|=1

#define CEPS 7.6293945e-06f     // 64 * 2^-23

__device__ __forceinline__ double sgn(double x) {
    return (x > 0.0) ? 1.0 : ((x < 0.0) ? -1.0 : 0.0);
}

// Fused prep: blocks 0..49 rays, 50..53 triangle tables, 54 scatter+emptyMask.
__global__ void prep_all(const float* __restrict__ p,
                         const float* __restrict__ l,
                         const float* __restrict__ hemi,
                         const float* __restrict__ V,
                         const int* __restrict__ indices,
                         const int* __restrict__ pointindex,
                         const float* __restrict__ COL,
                         const float* __restrict__ OPA,
                         double* __restrict__ ws,
                         unsigned* __restrict__ emptyMask,
                         float* __restrict__ out) {
    const int b = blockIdx.x, t = threadIdx.x;
    float* __restrict__ f32w = (float*)((char*)ws + F32_BYTE_OFF);
    if (b < 50) {
        int idx = b * 256 + t;                 // < 12800 exactly
        int pi = idx / NS, si = idx % NS;
        double px = p[pi*3+0], py = p[pi*3+1], pz = p[pi*3+2];
        double lx = l[0], ly = l[1], lz = l[2];
        double ux = lx - px, uy = ly - py, uz = lz - pz;
        double nrm = sqrt(ux*ux + uy*uy + uz*uz);
        ux /= nrm; uy /= nrm; uz /= nrm;
        double c = -uy;
        double wx = -uz, wz = ux;              // w = cross((0,-1,0), u_hat), wy=0
        double m01 = -wz, m10 = wz, m12 = -wx, m21 = wx;
        double q00 = m01*m10;
        double q02 = m01*m12;
        double q11 = m10*m01 + m12*m21;
        double q20 = m21*m10;
        double q22 = m21*m12;
        double ic = 1.0 + c;
        double r00 = 1.0 + q00/ic, r01 = m01,            r02 = q02/ic;
        double r10 = m10,          r11 = 1.0 + q11/ic,   r12 = m12;
        double r20 = q20/ic,       r21 = m21,            r22 = 1.0 + q22/ic;
        double hx = hemi[si*3+0], hy = hemi[si*3+1], hz = hemi[si*3+2];
        double dx = r00*hx + r01*hy + r02*hz + lx - px;
        double dy = r10*hx + r11*hy + r12*hz + ly - py;
        double dz = r20*hx + r21*hy + r22*hz + lz - pz;
        double* dsA = ws + DSA_OFF;
        dsA[idx*4+0] = dx;
        dsA[idx*4+1] = dy;
        dsA[idx*4+2] = dz;
        dsA[idx*4+3] = 0.0;
        *(float4*)(f32w + FD_OFF + idx*4) =
            make_float4((float)dx, (float)dy, (float)dz, 0.0f);
    } else if (b < 54) {
        int n = (b - 50) * 256 + t;            // < 1024 exactly
        const float* v = V + n*12;
        double a0=v[0], a1=v[1], a2=v[2];
        double b0=v[3], b1=v[4], b2=v[5];
        double c0=v[6], c1=v[7], c2=v[8];
        double v3x=v[9], v3y=v[10], v3z=v[11];
        double e1x=b0-a0, e1y=b1-a1, e1z=b2-a2;
        double e2x=c0-a0, e2y=c1-a1, e2z=c2-a2;
        double cx = e1y*e2z - e1z*e2y;
        double cy = e1z*e2x - e1x*e2z;
        double cz = e1x*e2y - e1y*e2x;
        double nn = sqrt(cx*cx + cy*cy + cz*cz);
        double nx = cx/nn, ny = cy/nn, nz = cz/nn;
        double kk = -(nx*v3x + ny*v3y + nz*v3z);
        double Bv = a0*b2 - a2*b0;
        double Dv = a0*b1 - a1*b0;
        double Ec = a0*c2 - a2*c0;
        double G2 = a1*c0 - a0*c1;
        double Fc = Bv*G2;
        double gd = Dv*(Ec*Dv + Fc);
        double gq = Dv*gd;
        double dq = Dv*c0;
        double aq = a0*gq;
        double WGr0 = a1*Bv - a2*Dv, WGr1 = -(a0*Bv), WGr2 = a0*Dv;
        double dg = Dv*G2;
        double WBr0 = -(a1*gd) + dg*WGr0;
        double WBr1 =  a0*gd  + dg*WGr1;
        double WBr2 =            dg*WGr2;
        double dd = Dv*dq;
        double WAr0 = gq - b0*WBr0 - dd*WGr0;
        double WAr1 =    - b0*WBr1 - dd*WGr1;
        double WAr2 =    - b0*WBr2 - dd*WGr2;
        double sg = sgn(Dv*gd), sb = sgn(gq), sa = sgn(aq);
        ws[NX_OFF + n] = nx;
        ws[NY_OFF + n] = ny;
        ws[NZ_OFF + n] = nz;
        ws[KK_OFF + n] = kk;
        double g0 = WGr0*sg, g1 = WGr1*sg, g2 = WGr2*sg;
        double bb0 = WBr0*sb, bb1 = WBr1*sb, bb2 = WBr2*sb;
        double aa0 = WAr0*sa, aa1 = WAr1*sa, aa2 = WAr2*sa;
        double* W = ws + W_OFF + n*10;
        W[0]=g0; W[1]=g1; W[2]=g2;
        W[3]=bb0; W[4]=bb1; W[5]=bb2;
        W[6]=aa0; W[7]=aa1; W[8]=aa2;
        W[9]=0.0;
        f32w[FNX_OFF+n]=(float)nx; f32w[FNY_OFF+n]=(float)ny;
        f32w[FNZ_OFF+n]=(float)nz; f32w[FKK_OFF+n]=(float)kk;
        double wsg = fabs(g0)+fabs(g1)+fabs(g2);
        double wsb = fabs(bb0)+fabs(bb1)+fabs(bb2);
        double wsa = fabs(aa0)+fabs(aa1)+fabs(aa2);
        double ig = wsg>0.0 ? 1.0/wsg : 0.0;
        double ib = wsb>0.0 ? 1.0/wsb : 0.0;
        double ia = wsa>0.0 ? 1.0/wsa : 0.0;
        float* fw = f32w + FW_OFF + n*12;
        fw[0]=(float)(g0*ig);  fw[1]=(float)(g1*ig);  fw[2]=(float)(g2*ig);
        fw[3]=(float)(bb0*ib); fw[4]=(float)(bb1*ib); fw[5]=(float)(bb2*ib);
        fw[6]=(float)(aa0*ia); fw[7]=(float)(aa1*ia); fw[8]=(float)(aa2*ia);
        fw[9]=0.0f; fw[10]=0.0f; fw[11]=0.0f;
    } else {
        emptyMask[t] = 0u;
        emptyMask[t + 256] = 0u;
        __syncthreads();
        for (int i = t; i < NP; i += 256) {
            int pidx = pointindex[i];
            int local = pidx & (NP - 1);
            int surf = indices[pidx*2 + 0];
            int mat  = indices[pidx*2 + 1];
            atomicOr(&emptyMask[local], 1u << surf);
            float* colOut = out + MASKN;
            float* opaOut = out + MASKN + 3*NP;
            float* refOut = out + MASKN + 4*NP;
            colOut[i*3+0] = COL[(surf*8+mat)*3+0];
            colOut[i*3+1] = COL[(surf*8+mat)*3+1];
            colOut[i*3+2] = COL[(surf*8+mat)*3+2];
            float o = OPA[surf*8+mat];
            opaOut[i] = fminf(fmaxf(o, 0.0f), 1.0f);
            refOut[i*3+0] = (float)((double)l[0] - (double)p[i*3+0]);
            refOut[i*3+1] = (float)((double)l[1] - (double)p[i*3+1]);
            refOut[i*3+2] = (float)((double)l[2] - (double)p[i*3+2]);
            double* pd = ws + PD_OFF;
            pd[i*4+0] = (double)p[i*3+0];
            pd[i*4+1] = (double)p[i*3+1];
            pd[i*4+2] = (double)p[i*3+2];
            pd[i*4+3] = 0.0;
            *(float4*)(f32w + FPD_OFF + i*4) =
                make_float4(p[i*3+0], p[i*3+1], p[i*3+2], 0.0f);
        }
    }
}

// Exact f64 recheck (sign tests only; empty handled by caller). Rare.
__device__ __noinline__ unsigned recheck64(const double* __restrict__ ws,
        unsigned ps, unsigned pp, unsigned n, unsigned nn, unsigned ss) {
    const double* s = ws + DSA_OFF + ps*4u;
    const double* o = ws + PD_OFF + pp*4u;
    double nx = ws[NX_OFF+n], ny = ws[NY_OFF+n], nz = ws[NZ_OFF+n];
    double kk = ws[KK_OFF+n];
    double vd = fma(s[2], nz, fma(s[1], ny, s[0]*nx));
    double tt = fma(o[2], nz, fma(o[1], ny, fma(o[0], nx, kk)));
    double e1 = fma(1e-4, vd, -tt);
    double e2 = vd + tt;
    const double* d = ws + DSA_OFF + (pp*25u + ss)*4u;
    double R0 = fma(-tt, d[0], vd*o[0]);
    double R1 = fma(-tt, d[1], vd*o[1]);
    double R2 = fma(-tt, d[2], vd*o[2]);
    const double* w = ws + W_OFF + nn*10u;
    double dG = fma(R2, w[2], fma(R1, w[1], R0*w[0]));
    double dB = fma(R2, w[5], fma(R1, w[4], R0*w[3]));
    double dA = fma(R2, w[8], fma(R1, w[7], R0*w[6]));
    int hv = __double2hiint(vd);
    int m = (__double2hiint(e1)^hv) | (__double2hiint(e2)^hv)
          | (__double2hiint(dG)^hv) | (__double2hiint(dB)^hv)
          | (__double2hiint(dA)^hv);
    return (m >= 0) ? 1u : 0u;
}

// Round 10: R7's proven shape (12800 blocks = one ps-line each, 4 elems/thread,
// high TLP+ILP) with the w-rows moved from LDS to GLOBAL registers:
// a thread's 4 consecutive rem span <=2 w-rows -> load rows nnA, nnA+1 once
// (6 coalesced float4 from the L2-resident 48KB table), select per element.
// Per-element LDS: ONE b128 (sdr[ss]). LDS pipe ~5x lighter than R7.
__global__ __launch_bounds__(256) void diffuse_main(
        const double* __restrict__ ws,
        const unsigned* __restrict__ emptyMask,
        float* __restrict__ out) {
    __shared__ float4 sdr[NS];

    const float* __restrict__ f32 = (const float*)((const char*)ws + F32_BYTE_OFF);
    const unsigned ps = blockIdx.x;
    const unsigned pp = ps / 25u;
    const unsigned q  = ps - pp*25u;
    const unsigned tid = threadIdx.x;
    const unsigned n0 = tid * 4u;

    const unsigned rem0 = (q << 10) + n0;
    const unsigned nnA = rem0 / 25u;
    const unsigned ssA = rem0 - nnA*25u;
    const unsigned nnB = (nnA < 1023u) ? (nnA + 1u) : 1023u;

    // global loads, all issued before the LDS barrier (latency hidden)
    const float4 wA0 = *(const float4*)(f32 + FW_OFF + nnA*12u);
    const float4 wA1 = *(const float4*)(f32 + FW_OFF + nnA*12u + 4u);
    const float4 wA2 = *(const float4*)(f32 + FW_OFF + nnA*12u + 8u);
    const float4 wB0 = *(const float4*)(f32 + FW_OFF + nnB*12u);
    const float4 wB1 = *(const float4*)(f32 + FW_OFF + nnB*12u + 4u);
    const float4 wB2 = *(const float4*)(f32 + FW_OFF + nnB*12u + 8u);
    const float4 fnx = *(const float4*)(f32 + FNX_OFF + n0);
    const float4 fny = *(const float4*)(f32 + FNY_OFF + n0);
    const float4 fnz = *(const float4*)(f32 + FNZ_OFF + n0);
    const float4 fkk = *(const float4*)(f32 + FKK_OFF + n0);
    const float sx = f32[FD_OFF + ps*4u + 0];
    const float sy = f32[FD_OFF + ps*4u + 1];
    const float sz = f32[FD_OFF + ps*4u + 2];
    const float ox = f32[FPD_OFF + pp*4u + 0];
    const float oy = f32[FPD_OFF + pp*4u + 1];
    const float oz = f32[FPD_OFF + pp*4u + 2];
    const unsigned em = (q == 0u) ? emptyMask[pp] : 0u;

    if (tid < 25u) {
        float4 dr = *(const float4*)(f32 + FD_OFF + (pp*25u + tid)*4u);
        dr.w = fmaxf(fabsf(dr.x), fmaxf(fabsf(dr.y), fabsf(dr.z)));
        sdr[tid] = dr;
    }
    __syncthreads();

    const float S1u = fabsf(sx) + fabsf(sy) + fabsf(sz);
    const float O1u = fabsf(ox) + fabsf(oy) + fabsf(oz);
    const float SOu = S1u * O1u;
    const float Evd = CEPS * S1u;

    const float nxk[4] = {fnx.x, fnx.y, fnx.z, fnx.w};
    const float nyk[4] = {fny.x, fny.y, fny.z, fny.w};
    const float nzk[4] = {fnz.x, fnz.y, fnz.z, fnz.w};
    const float kkk[4] = {fkk.x, fkk.y, fkk.z, fkk.w};

    float res[4];
    unsigned flg = 0u;
    #pragma unroll
    for (int k = 0; k < 4; ++k) {
        const bool useB = (ssA + (unsigned)k >= 25u);
        const unsigned ss = ssA + (unsigned)k - (useB ? 25u : 0u);
        const unsigned nn = useB ? nnB : nnA;
        // 9 scalar selects (k=0 folds to row A at compile time)
        const float wg0 = useB ? wB0.x : wA0.x;
        const float wg1 = useB ? wB0.y : wA0.y;
        const float wg2 = useB ? wB0.z : wA0.z;
        const float wb0 = useB ? wB0.w : wA0.w;
        const float wb1 = useB ? wB1.x : wA1.x;
        const float wb2 = useB ? wB1.y : wA1.y;
        const float wa0 = useB ? wB1.z : wA1.z;
        const float wa1 = useB ? wB1.w : wA1.w;
        const float wa2 = useB ? wB2.x : wA2.x;

        const float nx = nxk[k], ny = nyk[k], nz = nzk[k], kk = kkk[k];
        const float vd = fmaf(sz, nz, fmaf(sy, ny, sx*nx));
        const float tt = fmaf(oz, nz, fmaf(oy, ny, fmaf(ox, nx, kk)));
        const float e1 = fmaf(1e-4f, vd, -tt);     // t > -1e-4
        const float e2 = vd + tt;                  // t < 1

        const float4 d4 = sdr[ss];                 // ONE LDS b128 per element
        const float R0 = fmaf(-tt, d4.x, vd*ox);
        const float R1 = fmaf(-tt, d4.y, vd*oy);
        const float R2 = fmaf(-tt, d4.z, vd*oz);

        const float dG = fmaf(R2, wg2, fmaf(R1, wg1, R0*wg0));
        const float dB = fmaf(R2, wb2, fmaf(R1, wb1, R0*wb0));
        const float dA = fmaf(R2, wa2, fmaf(R1, wa1, R0*wa0));

        const int hv = __float_as_int(vd);
        const int msk = (__float_as_int(e1)^hv) | (__float_as_int(e2)^hv)
                      | (__float_as_int(dG)^hv) | (__float_as_int(dB)^hv)
                      | (__float_as_int(dA)^hv);
        bool ok = (msk >= 0) && !((nn < 8u) && ((em >> nn) & 1u));
        res[k] = ok ? 1.0f : 0.0f;

        // rounding-error guards (identical semantics to rounds 7-9)
        const float akk = fabsf(kk);
        const float Ee  = CEPS * (S1u + O1u + akk);
        const float Mtt = O1u + akk;
        const float MR  = fmaf(Mtt, d4.w, SOu);
        const float Edx = CEPS * MR;
        const float mind = fminf(fabsf(dG), fminf(fabsf(dB), fabsf(dA)));
        const bool flag = (fabsf(vd) < Evd) | (fabsf(e1) < Ee)
                        | (fabsf(e2) < Ee) | (mind < Edx);
        flg |= ((unsigned)flag) << k;
    }

    if (__builtin_expect(flg != 0u, 0)) {
        unsigned f2 = flg;
        while (f2) {
            const unsigned k = (unsigned)__ffs(f2) - 1u;
            f2 &= f2 - 1u;
            const bool useB = (ssA + k >= 25u);
            const unsigned ss = ssA + k - (useB ? 25u : 0u);
            const unsigned nn = useB ? nnB : nnA;
            const unsigned bit = recheck64(ws, ps, pp, n0 + k, nn, ss);
            const bool okEmpty = !((nn < 8u) && ((em >> nn) & 1u));
            res[k] = (bit && okEmpty) ? 1.0f : 0.0f;
        }
    }
    *(float4*)(out + (ps << 10) + n0) = make_float4(res[0], res[1], res[2], res[3]);
}

extern "C" void kernel_launch(void* const* d_in, const int* in_sizes, int n_in,
                              void* d_out, int out_size, void* d_ws, size_t ws_size,
                              hipStream_t stream) {
    const float* V         = (const float*)d_in[0];
    const int*   indices   = (const int*)  d_in[1];
    const int*   pointindex= (const int*)  d_in[2];
    const float* COL       = (const float*)d_in[3];
    const float* OPA       = (const float*)d_in[4];
    const float* p         = (const float*)d_in[5];
    const float* l         = (const float*)d_in[6];
    // d_in[7] = normals (unused), d_in[8] = it (unused)
    const float* hemi      = (const float*)d_in[9];

    float* out = (float*)d_out;
    double* ws = (double*)d_ws;
    unsigned* emptyMask = (unsigned*)((char*)d_ws + EMPTY_OFF);

    prep_all<<<55, 256, 0, stream>>>(p, l, hemi, V, indices, pointindex,
                                     COL, OPA, ws, emptyMask, out);
    diffuse_main<<<NPS, 256, 0, stream>>>(ws, emptyMask, out);
}

// Round 11
// 36.279 us; speedup vs baseline: 1.0734x; 1.0071x over previous
//
#include <hip/hip_runtime.h>
#include <math.h>

#define NP   512
#define NT   1024
#define NS   25
#define NPS  (NP*NS)            // 12800
#define MASKN (NP*NT*NS)        // 13107200

// ---- f64 region (double offsets) ----
#define DSA_OFF  0              // dsA [NPS][4]
#define PD_OFF   51200          // pd  [NP][4]
#define NX_OFF   53248
#define NY_OFF   54272
#define NZ_OFF   55296
#define KK_OFF   56320
#define W_OFF    57344          // W64 [NT][10] sign-folded
#define EMPTY_OFF ((size_t)67584 * 8)      // u32[512]
// ---- f32 shadow region (float offsets from F32 base) ----
#define F32_BYTE_OFF (EMPTY_OFF + 2048)
#define FD_OFF   0              // d32  [NPS][4]
#define FPD_OFF  51200          // pd32 [NP][4]
#define FNX_OFF  53248
#define FNY_OFF  54272
#define FNZ_OFF  55296
#define FKK_OFF  56320
#define FW_OFF   57344          // W32 [NT][12], rows prescaled to sum|w|=1

#define CEPS 7.6293945e-06f     // 64 * 2^-23

__device__ __forceinline__ double sgn(double x) {
    return (x > 0.0) ? 1.0 : ((x < 0.0) ? -1.0 : 0.0);
}

// Fused prep: blocks 0..49 rays, 50..53 triangle tables, 54 scatter+emptyMask.
__global__ void prep_all(const float* __restrict__ p,
                         const float* __restrict__ l,
                         const float* __restrict__ hemi,
                         const float* __restrict__ V,
                         const int* __restrict__ indices,
                         const int* __restrict__ pointindex,
                         const float* __restrict__ COL,
                         const float* __restrict__ OPA,
                         double* __restrict__ ws,
                         unsigned* __restrict__ emptyMask,
                         float* __restrict__ out) {
    const int b = blockIdx.x, t = threadIdx.x;
    float* __restrict__ f32w = (float*)((char*)ws + F32_BYTE_OFF);
    if (b < 50) {
        int idx = b * 256 + t;                 // < 12800 exactly
        int pi = idx / NS, si = idx % NS;
        double px = p[pi*3+0], py = p[pi*3+1], pz = p[pi*3+2];
        double lx = l[0], ly = l[1], lz = l[2];
        double ux = lx - px, uy = ly - py, uz = lz - pz;
        double nrm = sqrt(ux*ux + uy*uy + uz*uz);
        ux /= nrm; uy /= nrm; uz /= nrm;
        double c = -uy;
        double wx = -uz, wz = ux;              // w = cross((0,-1,0), u_hat), wy=0
        double m01 = -wz, m10 = wz, m12 = -wx, m21 = wx;
        double q00 = m01*m10;
        double q02 = m01*m12;
        double q11 = m10*m01 + m12*m21;
        double q20 = m21*m10;
        double q22 = m21*m12;
        double ic = 1.0 + c;
        double r00 = 1.0 + q00/ic, r01 = m01,            r02 = q02/ic;
        double r10 = m10,          r11 = 1.0 + q11/ic,   r12 = m12;
        double r20 = q20/ic,       r21 = m21,            r22 = 1.0 + q22/ic;
        double hx = hemi[si*3+0], hy = hemi[si*3+1], hz = hemi[si*3+2];
        double dx = r00*hx + r01*hy + r02*hz + lx - px;
        double dy = r10*hx + r11*hy + r12*hz + ly - py;
        double dz = r20*hx + r21*hy + r22*hz + lz - pz;
        double* dsA = ws + DSA_OFF;
        dsA[idx*4+0] = dx;
        dsA[idx*4+1] = dy;
        dsA[idx*4+2] = dz;
        dsA[idx*4+3] = 0.0;
        *(float4*)(f32w + FD_OFF + idx*4) =
            make_float4((float)dx, (float)dy, (float)dz, 0.0f);
    } else if (b < 54) {
        int n = (b - 50) * 256 + t;            // < 1024 exactly
        const float* v = V + n*12;
        double a0=v[0], a1=v[1], a2=v[2];
        double b0=v[3], b1=v[4], b2=v[5];
        double c0=v[6], c1=v[7], c2=v[8];
        double v3x=v[9], v3y=v[10], v3z=v[11];
        double e1x=b0-a0, e1y=b1-a1, e1z=b2-a2;
        double e2x=c0-a0, e2y=c1-a1, e2z=c2-a2;
        double cx = e1y*e2z - e1z*e2y;
        double cy = e1z*e2x - e1x*e2z;
        double cz = e1x*e2y - e1y*e2x;
        double nn = sqrt(cx*cx + cy*cy + cz*cz);
        double nx = cx/nn, ny = cy/nn, nz = cz/nn;
        double kk = -(nx*v3x + ny*v3y + nz*v3z);
        double Bv = a0*b2 - a2*b0;
        double Dv = a0*b1 - a1*b0;
        double Ec = a0*c2 - a2*c0;
        double G2 = a1*c0 - a0*c1;
        double Fc = Bv*G2;
        double gd = Dv*(Ec*Dv + Fc);
        double gq = Dv*gd;
        double dq = Dv*c0;
        double aq = a0*gq;
        double WGr0 = a1*Bv - a2*Dv, WGr1 = -(a0*Bv), WGr2 = a0*Dv;
        double dg = Dv*G2;
        double WBr0 = -(a1*gd) + dg*WGr0;
        double WBr1 =  a0*gd  + dg*WGr1;
        double WBr2 =            dg*WGr2;
        double dd = Dv*dq;
        double WAr0 = gq - b0*WBr0 - dd*WGr0;
        double WAr1 =    - b0*WBr1 - dd*WGr1;
        double WAr2 =    - b0*WBr2 - dd*WGr2;
        double sg = sgn(Dv*gd), sb = sgn(gq), sa = sgn(aq);
        ws[NX_OFF + n] = nx;
        ws[NY_OFF + n] = ny;
        ws[NZ_OFF + n] = nz;
        ws[KK_OFF + n] = kk;
        double g0 = WGr0*sg, g1 = WGr1*sg, g2 = WGr2*sg;
        double bb0 = WBr0*sb, bb1 = WBr1*sb, bb2 = WBr2*sb;
        double aa0 = WAr0*sa, aa1 = WAr1*sa, aa2 = WAr2*sa;
        double* W = ws + W_OFF + n*10;
        W[0]=g0; W[1]=g1; W[2]=g2;
        W[3]=bb0; W[4]=bb1; W[5]=bb2;
        W[6]=aa0; W[7]=aa1; W[8]=aa2;
        W[9]=0.0;
        f32w[FNX_OFF+n]=(float)nx; f32w[FNY_OFF+n]=(float)ny;
        f32w[FNZ_OFF+n]=(float)nz; f32w[FKK_OFF+n]=(float)kk;
        double wsg = fabs(g0)+fabs(g1)+fabs(g2);
        double wsb = fabs(bb0)+fabs(bb1)+fabs(bb2);
        double wsa = fabs(aa0)+fabs(aa1)+fabs(aa2);
        double ig = wsg>0.0 ? 1.0/wsg : 0.0;
        double ib = wsb>0.0 ? 1.0/wsb : 0.0;
        double ia = wsa>0.0 ? 1.0/wsa : 0.0;
        float* fw = f32w + FW_OFF + n*12;
        fw[0]=(float)(g0*ig);  fw[1]=(float)(g1*ig);  fw[2]=(float)(g2*ig);
        fw[3]=(float)(bb0*ib); fw[4]=(float)(bb1*ib); fw[5]=(float)(bb2*ib);
        fw[6]=(float)(aa0*ia); fw[7]=(float)(aa1*ia); fw[8]=(float)(aa2*ia);
        fw[9]=0.0f; fw[10]=0.0f; fw[11]=0.0f;
    } else {
        emptyMask[t] = 0u;
        emptyMask[t + 256] = 0u;
        __syncthreads();
        for (int i = t; i < NP; i += 256) {
            int pidx = pointindex[i];
            int local = pidx & (NP - 1);
            int surf = indices[pidx*2 + 0];
            int mat  = indices[pidx*2 + 1];
            atomicOr(&emptyMask[local], 1u << surf);
            float* colOut = out + MASKN;
            float* opaOut = out + MASKN + 3*NP;
            float* refOut = out + MASKN + 4*NP;
            colOut[i*3+0] = COL[(surf*8+mat)*3+0];
            colOut[i*3+1] = COL[(surf*8+mat)*3+1];
            colOut[i*3+2] = COL[(surf*8+mat)*3+2];
            float o = OPA[surf*8+mat];
            opaOut[i] = fminf(fmaxf(o, 0.0f), 1.0f);
            refOut[i*3+0] = (float)((double)l[0] - (double)p[i*3+0]);
            refOut[i*3+1] = (float)((double)l[1] - (double)p[i*3+1]);
            refOut[i*3+2] = (float)((double)l[2] - (double)p[i*3+2]);
            double* pd = ws + PD_OFF;
            pd[i*4+0] = (double)p[i*3+0];
            pd[i*4+1] = (double)p[i*3+1];
            pd[i*4+2] = (double)p[i*3+2];
            pd[i*4+3] = 0.0;
            *(float4*)(f32w + FPD_OFF + i*4) =
                make_float4(p[i*3+0], p[i*3+1], p[i*3+2], 0.0f);
        }
    }
}

// Exact f64 recheck (sign tests only; empty handled by caller). Rare.
__device__ __noinline__ unsigned recheck64(const double* __restrict__ ws,
        unsigned ps, unsigned pp, unsigned n, unsigned nn, unsigned ss) {
    const double* s = ws + DSA_OFF + ps*4u;
    const double* o = ws + PD_OFF + pp*4u;
    double nx = ws[NX_OFF+n], ny = ws[NY_OFF+n], nz = ws[NZ_OFF+n];
    double kk = ws[KK_OFF+n];
    double vd = fma(s[2], nz, fma(s[1], ny, s[0]*nx));
    double tt = fma(o[2], nz, fma(o[1], ny, fma(o[0], nx, kk)));
    double e1 = fma(1e-4, vd, -tt);
    double e2 = vd + tt;
    const double* d = ws + DSA_OFF + (pp*25u + ss)*4u;
    double R0 = fma(-tt, d[0], vd*o[0]);
    double R1 = fma(-tt, d[1], vd*o[1]);
    double R2 = fma(-tt, d[2], vd*o[2]);
    const double* w = ws + W_OFF + nn*10u;
    double dG = fma(R2, w[2], fma(R1, w[1], R0*w[0]));
    double dB = fma(R2, w[5], fma(R1, w[4], R0*w[3]));
    double dA = fma(R2, w[8], fma(R1, w[7], R0*w[6]));
    int hv = __double2hiint(vd);
    int m = (__double2hiint(e1)^hv) | (__double2hiint(e2)^hv)
          | (__double2hiint(dG)^hv) | (__double2hiint(dB)^hv)
          | (__double2hiint(dA)^hv);
    return (m >= 0) ? 1u : 0u;
}

// Round 11: R7 shape (12800 blocks, 4 elems/thread) with BALANCED pipes:
//   w-rows: staged once into LDS (0.5 VMEM/thread), read as 6 ds_read_b128
//           per THREAD (2 rows x 3 float4, hoisted before element loop)
//   d[ss]:  1 ds_read_b128 per element
//   n-tabs: 4 coalesced global float4 per thread (SoA)
// Per CU: LDS ~10us, VMEM ~8us, VALU ~8us -- overlapped across ~8 blocks/CU.
__global__ __launch_bounds__(256) void diffuse_main(
        const double* __restrict__ ws,
        const unsigned* __restrict__ emptyMask,
        float* __restrict__ out) {
    __shared__ float4 sW4[42*3];       // row r at [3r..3r+2]; 48B stride
    __shared__ float4 sdr[NS];

    const float* __restrict__ f32 = (const float*)((const char*)ws + F32_BYTE_OFF);
    const unsigned ps = blockIdx.x;
    const unsigned pp = ps / 25u;
    const unsigned q  = ps - pp*25u;
    const unsigned tid = threadIdx.x;
    const unsigned n0 = tid * 4u;

    const unsigned rem0 = (q << 10) + n0;
    const unsigned nnA = rem0 / 25u;
    const unsigned ssA = rem0 - nnA*25u;
    const unsigned nnB = nnA + 1u;             // LDS row always stageable
    const unsigned nn0b = (q << 10) / 25u;     // block's first w-row

    // global loads, all issued before the barrier (latency hidden)
    const float4 fnx = *(const float4*)(f32 + FNX_OFF + n0);
    const float4 fny = *(const float4*)(f32 + FNY_OFF + n0);
    const float4 fnz = *(const float4*)(f32 + FNZ_OFF + n0);
    const float4 fkk = *(const float4*)(f32 + FKK_OFF + n0);
    const float sx = f32[FD_OFF + ps*4u + 0];
    const float sy = f32[FD_OFF + ps*4u + 1];
    const float sz = f32[FD_OFF + ps*4u + 2];
    const float ox = f32[FPD_OFF + pp*4u + 0];
    const float oy = f32[FPD_OFF + pp*4u + 1];
    const float oz = f32[FPD_OFF + pp*4u + 2];
    const unsigned em = (q == 0u) ? emptyMask[pp] : 0u;

    // stage W window (42 rows x 3 float4) + ray d-vectors
    if (tid < 126u) {
        const unsigned row = tid / 3u, quad = tid - row*3u;
        unsigned gn = nn0b + row; if (gn > 1023u) gn = 1023u;
        sW4[tid] = *(const float4*)(f32 + FW_OFF + gn*12u + quad*4u);
    }
    if (tid < 25u) {
        float4 dr = *(const float4*)(f32 + FD_OFF + (pp*25u + tid)*4u);
        dr.w = fmaxf(fabsf(dr.x), fmaxf(fabsf(dr.y), fabsf(dr.z)));
        sdr[tid] = dr;
    }
    __syncthreads();

    // w rows A, B -> registers (6 ds_read_b128 per thread, reused 4 elems)
    const unsigned rA = (nnA - nn0b)*3u;
    const float4 wA0 = sW4[rA], wA1 = sW4[rA+1u], wA2 = sW4[rA+2u];
    const float4 wB0 = sW4[rA+3u], wB1 = sW4[rA+4u], wB2 = sW4[rA+5u];

    const float S1u = fabsf(sx) + fabsf(sy) + fabsf(sz);
    const float O1u = fabsf(ox) + fabsf(oy) + fabsf(oz);
    const float SOu = S1u * O1u;
    const float Evd = CEPS * S1u;

    const float nxk[4] = {fnx.x, fnx.y, fnx.z, fnx.w};
    const float nyk[4] = {fny.x, fny.y, fny.z, fny.w};
    const float nzk[4] = {fnz.x, fnz.y, fnz.z, fnz.w};
    const float kkk[4] = {fkk.x, fkk.y, fkk.z, fkk.w};

    float res[4];
    unsigned flg = 0u;
    #pragma unroll
    for (int k = 0; k < 4; ++k) {
        const bool useB = (ssA + (unsigned)k >= 25u);
        const unsigned ss = ssA + (unsigned)k - (useB ? 25u : 0u);
        const unsigned nn = useB ? nnB : nnA;
        const float wg0 = useB ? wB0.x : wA0.x;
        const float wg1 = useB ? wB0.y : wA0.y;
        const float wg2 = useB ? wB0.z : wA0.z;
        const float wb0 = useB ? wB0.w : wA0.w;
        const float wb1 = useB ? wB1.x : wA1.x;
        const float wb2 = useB ? wB1.y : wA1.y;
        const float wa0 = useB ? wB1.z : wA1.z;
        const float wa1 = useB ? wB1.w : wA1.w;
        const float wa2 = useB ? wB2.x : wA2.x;

        const float nx = nxk[k], ny = nyk[k], nz = nzk[k], kk = kkk[k];
        const float vd = fmaf(sz, nz, fmaf(sy, ny, sx*nx));
        const float tt = fmaf(oz, nz, fmaf(oy, ny, fmaf(ox, nx, kk)));
        const float e1 = fmaf(1e-4f, vd, -tt);     // t > -1e-4
        const float e2 = vd + tt;                  // t < 1

        const float4 d4 = sdr[ss];                 // ONE LDS b128 per element
        const float R0 = fmaf(-tt, d4.x, vd*ox);
        const float R1 = fmaf(-tt, d4.y, vd*oy);
        const float R2 = fmaf(-tt, d4.z, vd*oz);

        const float dG = fmaf(R2, wg2, fmaf(R1, wg1, R0*wg0));
        const float dB = fmaf(R2, wb2, fmaf(R1, wb1, R0*wb0));
        const float dA = fmaf(R2, wa2, fmaf(R1, wa1, R0*wa0));

        const int hv = __float_as_int(vd);
        const int msk = (__float_as_int(e1)^hv) | (__float_as_int(e2)^hv)
                      | (__float_as_int(dG)^hv) | (__float_as_int(dB)^hv)
                      | (__float_as_int(dA)^hv);
        bool ok = (msk >= 0) && !((nn < 8u) && ((em >> nn) & 1u));
        res[k] = ok ? 1.0f : 0.0f;

        // rounding-error guards (identical semantics to rounds 7-10)
        const float akk = fabsf(kk);
        const float Ee  = CEPS * (S1u + O1u + akk);
        const float Mtt = O1u + akk;
        const float MR  = fmaf(Mtt, d4.w, SOu);
        const float Edx = CEPS * MR;
        const float mind = fminf(fabsf(dG), fminf(fabsf(dB), fabsf(dA)));
        const bool flag = (fabsf(vd) < Evd) | (fabsf(e1) < Ee)
                        | (fabsf(e2) < Ee) | (mind < Edx);
        flg |= ((unsigned)flag) << k;
    }

    if (__builtin_expect(flg != 0u, 0)) {
        unsigned f2 = flg;
        while (f2) {
            const unsigned k = (unsigned)__ffs(f2) - 1u;
            f2 &= f2 - 1u;
            const bool useB = (ssA + k >= 25u);
            const unsigned ss = ssA + k - (useB ? 25u : 0u);
            const unsigned nn = useB ? nnB : nnA;
            const unsigned bit = recheck64(ws, ps, pp, n0 + k, nn, ss);
            const bool okEmpty = !((nn < 8u) && ((em >> nn) & 1u));
            res[k] = (bit && okEmpty) ? 1.0f : 0.0f;
        }
    }
    *(float4*)(out + (ps << 10) + n0) = make_float4(res[0], res[1], res[2], res[3]);
}

extern "C" void kernel_launch(void* const* d_in, const int* in_sizes, int n_in,
                              void* d_out, int out_size, void* d_ws, size_t ws_size,
                              hipStream_t stream) {
    const float* V         = (const float*)d_in[0];
    const int*   indices   = (const int*)  d_in[1];
    const int*   pointindex= (const int*)  d_in[2];
    const float* COL       = (const float*)d_in[3];
    const float* OPA       = (const float*)d_in[4];
    const float* p         = (const float*)d_in[5];
    const float* l         = (const float*)d_in[6];
    // d_in[7] = normals (unused), d_in[8] = it (unused)
    const float* hemi      = (const float*)d_in[9];

    float* out = (float*)d_out;
    double* ws = (double*)d_ws;
    unsigned* emptyMask = (unsigned*)((char*)d_ws + EMPTY_OFF);

    prep_all<<<55, 256, 0, stream>>>(p, l, hemi, V, indices, pointindex,
                                     COL, OPA, ws, emptyMask, out);
    diffuse_main<<<NPS, 256, 0, stream>>>(ws, emptyMask, out);
}

// Round 12
// 34.778 us; speedup vs baseline: 1.1197x; 1.0432x over previous
//
#include <hip/hip_runtime.h>
#include <math.h>

#define NP   512
#define NT   1024
#define NS   25
#define NPS  (NP*NS)            // 12800
#define MASKN (NP*NT*NS)        // 13107200

// ---- f64 region (double offsets) ----
#define DSA_OFF  0              // dsA [NPS][4]
#define PD_OFF   51200          // pd  [NP][4]
#define NX_OFF   53248
#define NY_OFF   54272
#define NZ_OFF   55296
#define KK_OFF   56320
#define W_OFF    57344          // W64 [NT][10] sign-folded
#define EMPTY_OFF ((size_t)67584 * 8)      // u32[512]
// ---- f32 shadow region (float offsets from F32 base) ----
#define F32_BYTE_OFF (EMPTY_OFF + 2048)
#define FD_OFF   0              // d32  [NPS][4]
#define FPD_OFF  51200          // pd32 [NP][4]
#define FNX_OFF  53248
#define FNY_OFF  54272
#define FNZ_OFF  55296
#define FKK_OFF  56320
#define FW_OFF   57344          // W32 [NT][12], rows prescaled to sum|w|=1

#define CEPS 7.6293945e-06f     // 64 * 2^-23

__device__ __forceinline__ double sgn(double x) {
    return (x > 0.0) ? 1.0 : ((x < 0.0) ? -1.0 : 0.0);
}

// Fused prep: blocks 0..49 rays, 50..53 triangle tables, 54 scatter+emptyMask.
__global__ void prep_all(const float* __restrict__ p,
                         const float* __restrict__ l,
                         const float* __restrict__ hemi,
                         const float* __restrict__ V,
                         const int* __restrict__ indices,
                         const int* __restrict__ pointindex,
                         const float* __restrict__ COL,
                         const float* __restrict__ OPA,
                         double* __restrict__ ws,
                         unsigned* __restrict__ emptyMask,
                         float* __restrict__ out) {
    const int b = blockIdx.x, t = threadIdx.x;
    float* __restrict__ f32w = (float*)((char*)ws + F32_BYTE_OFF);
    if (b < 50) {
        int idx = b * 256 + t;                 // < 12800 exactly
        int pi = idx / NS, si = idx % NS;
        double px = p[pi*3+0], py = p[pi*3+1], pz = p[pi*3+2];
        double lx = l[0], ly = l[1], lz = l[2];
        double ux = lx - px, uy = ly - py, uz = lz - pz;
        double nrm = sqrt(ux*ux + uy*uy + uz*uz);
        ux /= nrm; uy /= nrm; uz /= nrm;
        double c = -uy;
        double wx = -uz, wz = ux;              // w = cross((0,-1,0), u_hat), wy=0
        double m01 = -wz, m10 = wz, m12 = -wx, m21 = wx;
        double q00 = m01*m10;
        double q02 = m01*m12;
        double q11 = m10*m01 + m12*m21;
        double q20 = m21*m10;
        double q22 = m21*m12;
        double ic = 1.0 + c;
        double r00 = 1.0 + q00/ic, r01 = m01,            r02 = q02/ic;
        double r10 = m10,          r11 = 1.0 + q11/ic,   r12 = m12;
        double r20 = q20/ic,       r21 = m21,            r22 = 1.0 + q22/ic;
        double hx = hemi[si*3+0], hy = hemi[si*3+1], hz = hemi[si*3+2];
        double dx = r00*hx + r01*hy + r02*hz + lx - px;
        double dy = r10*hx + r11*hy + r12*hz + ly - py;
        double dz = r20*hx + r21*hy + r22*hz + lz - pz;
        double* dsA = ws + DSA_OFF;
        dsA[idx*4+0] = dx;
        dsA[idx*4+1] = dy;
        dsA[idx*4+2] = dz;
        dsA[idx*4+3] = 0.0;
        *(float4*)(f32w + FD_OFF + idx*4) =
            make_float4((float)dx, (float)dy, (float)dz, 0.0f);
    } else if (b < 54) {
        int n = (b - 50) * 256 + t;            // < 1024 exactly
        const float* v = V + n*12;
        double a0=v[0], a1=v[1], a2=v[2];
        double b0=v[3], b1=v[4], b2=v[5];
        double c0=v[6], c1=v[7], c2=v[8];
        double v3x=v[9], v3y=v[10], v3z=v[11];
        double e1x=b0-a0, e1y=b1-a1, e1z=b2-a2;
        double e2x=c0-a0, e2y=c1-a1, e2z=c2-a2;
        double cx = e1y*e2z - e1z*e2y;
        double cy = e1z*e2x - e1x*e2z;
        double cz = e1x*e2y - e1y*e2x;
        double nn = sqrt(cx*cx + cy*cy + cz*cz);
        double nx = cx/nn, ny = cy/nn, nz = cz/nn;
        double kk = -(nx*v3x + ny*v3y + nz*v3z);
        double Bv = a0*b2 - a2*b0;
        double Dv = a0*b1 - a1*b0;
        double Ec = a0*c2 - a2*c0;
        double G2 = a1*c0 - a0*c1;
        double Fc = Bv*G2;
        double gd = Dv*(Ec*Dv + Fc);
        double gq = Dv*gd;
        double dq = Dv*c0;
        double aq = a0*gq;
        double WGr0 = a1*Bv - a2*Dv, WGr1 = -(a0*Bv), WGr2 = a0*Dv;
        double dg = Dv*G2;
        double WBr0 = -(a1*gd) + dg*WGr0;
        double WBr1 =  a0*gd  + dg*WGr1;
        double WBr2 =            dg*WGr2;
        double dd = Dv*dq;
        double WAr0 = gq - b0*WBr0 - dd*WGr0;
        double WAr1 =    - b0*WBr1 - dd*WGr1;
        double WAr2 =    - b0*WBr2 - dd*WGr2;
        double sg = sgn(Dv*gd), sb = sgn(gq), sa = sgn(aq);
        ws[NX_OFF + n] = nx;
        ws[NY_OFF + n] = ny;
        ws[NZ_OFF + n] = nz;
        ws[KK_OFF + n] = kk;
        double g0 = WGr0*sg, g1 = WGr1*sg, g2 = WGr2*sg;
        double bb0 = WBr0*sb, bb1 = WBr1*sb, bb2 = WBr2*sb;
        double aa0 = WAr0*sa, aa1 = WAr1*sa, aa2 = WAr2*sa;
        double* W = ws + W_OFF + n*10;
        W[0]=g0; W[1]=g1; W[2]=g2;
        W[3]=bb0; W[4]=bb1; W[5]=bb2;
        W[6]=aa0; W[7]=aa1; W[8]=aa2;
        W[9]=0.0;
        f32w[FNX_OFF+n]=(float)nx; f32w[FNY_OFF+n]=(float)ny;
        f32w[FNZ_OFF+n]=(float)nz; f32w[FKK_OFF+n]=(float)kk;
        double wsg = fabs(g0)+fabs(g1)+fabs(g2);
        double wsb = fabs(bb0)+fabs(bb1)+fabs(bb2);
        double wsa = fabs(aa0)+fabs(aa1)+fabs(aa2);
        double ig = wsg>0.0 ? 1.0/wsg : 0.0;
        double ib = wsb>0.0 ? 1.0/wsb : 0.0;
        double ia = wsa>0.0 ? 1.0/wsa : 0.0;
        float* fw = f32w + FW_OFF + n*12;
        fw[0]=(float)(g0*ig);  fw[1]=(float)(g1*ig);  fw[2]=(float)(g2*ig);
        fw[3]=(float)(bb0*ib); fw[4]=(float)(bb1*ib); fw[5]=(float)(bb2*ib);
        fw[6]=(float)(aa0*ia); fw[7]=(float)(aa1*ia); fw[8]=(float)(aa2*ia);
        fw[9]=0.0f; fw[10]=0.0f; fw[11]=0.0f;
    } else {
        emptyMask[t] = 0u;
        emptyMask[t + 256] = 0u;
        __syncthreads();
        for (int i = t; i < NP; i += 256) {
            int pidx = pointindex[i];
            int local = pidx & (NP - 1);
            int surf = indices[pidx*2 + 0];
            int mat  = indices[pidx*2 + 1];
            atomicOr(&emptyMask[local], 1u << surf);
            float* colOut = out + MASKN;
            float* opaOut = out + MASKN + 3*NP;
            float* refOut = out + MASKN + 4*NP;
            colOut[i*3+0] = COL[(surf*8+mat)*3+0];
            colOut[i*3+1] = COL[(surf*8+mat)*3+1];
            colOut[i*3+2] = COL[(surf*8+mat)*3+2];
            float o = OPA[surf*8+mat];
            opaOut[i] = fminf(fmaxf(o, 0.0f), 1.0f);
            refOut[i*3+0] = (float)((double)l[0] - (double)p[i*3+0]);
            refOut[i*3+1] = (float)((double)l[1] - (double)p[i*3+1]);
            refOut[i*3+2] = (float)((double)l[2] - (double)p[i*3+2]);
            double* pd = ws + PD_OFF;
            pd[i*4+0] = (double)p[i*3+0];
            pd[i*4+1] = (double)p[i*3+1];
            pd[i*4+2] = (double)p[i*3+2];
            pd[i*4+3] = 0.0;
            *(float4*)(f32w + FPD_OFF + i*4) =
                make_float4(p[i*3+0], p[i*3+1], p[i*3+2], 0.0f);
        }
    }
}

// Exact f64 recheck (sign tests only; empty handled by caller). Rare.
__device__ __noinline__ unsigned recheck64(const double* __restrict__ ws,
        unsigned ps, unsigned pp, unsigned n, unsigned nn, unsigned ss) {
    const double* s = ws + DSA_OFF + ps*4u;
    const double* o = ws + PD_OFF + pp*4u;
    double nx = ws[NX_OFF+n], ny = ws[NY_OFF+n], nz = ws[NZ_OFF+n];
    double kk = ws[KK_OFF+n];
    double vd = fma(s[2], nz, fma(s[1], ny, s[0]*nx));
    double tt = fma(o[2], nz, fma(o[1], ny, fma(o[0], nx, kk)));
    double e1 = fma(1e-4, vd, -tt);
    double e2 = vd + tt;
    const double* d = ws + DSA_OFF + (pp*25u + ss)*4u;
    double R0 = fma(-tt, d[0], vd*o[0]);
    double R1 = fma(-tt, d[1], vd*o[1]);
    double R2 = fma(-tt, d[2], vd*o[2]);
    const double* w = ws + W_OFF + nn*10u;
    double dG = fma(R2, w[2], fma(R1, w[1], R0*w[0]));
    double dB = fma(R2, w[5], fma(R1, w[4], R0*w[3]));
    double dA = fma(R2, w[8], fma(R1, w[7], R0*w[6]));
    int hv = __double2hiint(vd);
    int m = (__double2hiint(e1)^hv) | (__double2hiint(e2)^hv)
          | (__double2hiint(dG)^hv) | (__double2hiint(dB)^hv)
          | (__double2hiint(dA)^hv);
    return (m >= 0) ? 1u : 0u;
}

// Round 12: R7's exact structure (best measured: 33.6us) with one local trim:
// the per-element d-vector read is ONE ds_read_b128 (float4 with |d|max in .w)
// instead of four b32 reads. w stays as per-element LDS b32 reads (keeps VGPR
// low -- every variant that hoisted w into registers regressed).
__global__ __launch_bounds__(256) void diffuse_main(
        const double* __restrict__ ws,
        const unsigned* __restrict__ emptyMask,
        float* __restrict__ out) {
    __shared__ float sW[42][12];
    __shared__ float4 sdr[NS];

    const float* __restrict__ f32 = (const float*)((const char*)ws + F32_BYTE_OFF);
    const unsigned ps = blockIdx.x;
    const unsigned pp = ps / 25u;
    const unsigned q  = ps - pp*25u;
    const unsigned nn0 = (q << 10) / 25u;
    const unsigned tid = threadIdx.x;
    const unsigned n0 = tid * 4u;

    // per-thread coalesced table loads (f32), issued before barrier
    const float4 fnx = *(const float4*)(f32 + FNX_OFF + n0);
    const float4 fny = *(const float4*)(f32 + FNY_OFF + n0);
    const float4 fnz = *(const float4*)(f32 + FNZ_OFF + n0);
    const float4 fkk = *(const float4*)(f32 + FKK_OFF + n0);
    // block-uniform scalars
    const float sx = f32[FD_OFF + ps*4u + 0];
    const float sy = f32[FD_OFF + ps*4u + 1];
    const float sz = f32[FD_OFF + ps*4u + 2];
    const float ox = f32[FPD_OFF + pp*4u + 0];
    const float oy = f32[FPD_OFF + pp*4u + 1];
    const float oz = f32[FPD_OFF + pp*4u + 2];
    const unsigned em = (q == 0u) ? emptyMask[pp] : 0u;
    const float S1u = fabsf(sx) + fabsf(sy) + fabsf(sz);
    const float O1u = fabsf(ox) + fabsf(oy) + fabsf(oz);
    const float Evd = CEPS * S1u;
    const float Eb0 = S1u + O1u;          // e1/e2 magnitude base
    const float SOu = S1u * O1u;          // vd*o magnitude base for R

    // stage W window (42 rows x 12 floats) + ray d-vectors
    if (tid < 126u) {
        unsigned row = tid / 3u, quad = tid - row*3u;
        unsigned gn = nn0 + row; if (gn > 1023u) gn = 1023u;
        const float4 v = *(const float4*)(f32 + FW_OFF + gn*12u + quad*4u);
        *(float4*)(&sW[row][quad*4u]) = v;
    }
    if (tid < 25u) {
        float4 dr = *(const float4*)(f32 + FD_OFF + (pp*25u + tid)*4u);
        dr.w = fmaxf(fabsf(dr.x), fmaxf(fabsf(dr.y), fabsf(dr.z)));
        sdr[tid] = dr;
    }
    __syncthreads();

    const float nxk[4] = {fnx.x, fnx.y, fnx.z, fnx.w};
    const float nyk[4] = {fny.x, fny.y, fny.z, fny.w};
    const float nzk[4] = {fnz.x, fnz.y, fnz.z, fnz.w};
    const float kkk[4] = {fkk.x, fkk.y, fkk.z, fkk.w};

    unsigned rem = (q << 10) + n0;
    unsigned nn = rem / 25u;
    unsigned ss = rem - nn*25u;

    float res[4];
    #pragma unroll
    for (int k = 0; k < 4; ++k) {
        const float nx = nxk[k], ny = nyk[k], nz = nzk[k], kk = kkk[k];
        const float vd = fmaf(sz, nz, fmaf(sy, ny, sx*nx));
        const float tt = fmaf(oz, nz, fmaf(oy, ny, fmaf(ox, nx, kk)));
        const float e1 = fmaf(1e-4f, vd, -tt);     // t > -1e-4
        const float e2 = vd + tt;                  // t < 1

        const float4 d4 = sdr[ss];                 // ONE LDS b128
        const float R0 = fmaf(-tt, d4.x, vd*ox);
        const float R1 = fmaf(-tt, d4.y, vd*oy);
        const float R2 = fmaf(-tt, d4.z, vd*oz);

        const float* w = sW[nn - nn0];
        const float dG = fmaf(R2, w[2], fmaf(R1, w[1], R0*w[0]));
        const float dB = fmaf(R2, w[5], fmaf(R1, w[4], R0*w[3]));
        const float dA = fmaf(R2, w[8], fmaf(R1, w[7], R0*w[6]));

        const int hv = __float_as_int(vd);
        int msk = (__float_as_int(e1)^hv) | (__float_as_int(e2)^hv)
                | (__float_as_int(dG)^hv) | (__float_as_int(dB)^hv)
                | (__float_as_int(dA)^hv);
        bool ok = (msk >= 0) && !((nn < 8u) && ((em >> nn) & 1u));

        // rounding-error guards (identical semantics to rounds 7-11)
        const float akk = fabsf(kk);
        const float Ee  = CEPS * (Eb0 + akk);
        const float Mtt = O1u + akk;
        const float MR  = fmaf(Mtt, d4.w, SOu);
        const float Edx = CEPS * MR;
        const float mind = fminf(fabsf(dG), fminf(fabsf(dB), fabsf(dA)));
        const bool flag = (fabsf(vd) < Evd) | (fabsf(e1) < Ee)
                        | (fabsf(e2) < Ee) | (mind < Edx);

        float r = ok ? 1.0f : 0.0f;
        if (__builtin_expect(flag, 0)) {
            const unsigned bit = recheck64(ws, ps, pp, n0 + (unsigned)k, nn, ss);
            const bool okEmpty = !((nn < 8u) && ((em >> nn) & 1u));
            r = (bit && okEmpty) ? 1.0f : 0.0f;
        }
        res[k] = r;

        ss += 1u;
        const bool wrap = (ss == 25u);
        nn += wrap ? 1u : 0u;
        ss  = wrap ? 0u : ss;
    }
    *(float4*)(out + (ps << 10) + n0) = make_float4(res[0], res[1], res[2], res[3]);
}

extern "C" void kernel_launch(void* const* d_in, const int* in_sizes, int n_in,
                              void* d_out, int out_size, void* d_ws, size_t ws_size,
                              hipStream_t stream) {
    const float* V         = (const float*)d_in[0];
    const int*   indices   = (const int*)  d_in[1];
    const int*   pointindex= (const int*)  d_in[2];
    const float* COL       = (const float*)d_in[3];
    const float* OPA       = (const float*)d_in[4];
    const float* p         = (const float*)d_in[5];
    const float* l         = (const float*)d_in[6];
    // d_in[7] = normals (unused), d_in[8] = it (unused)
    const float* hemi      = (const float*)d_in[9];

    float* out = (float*)d_out;
    double* ws = (double*)d_ws;
    unsigned* emptyMask = (unsigned*)((char*)d_ws + EMPTY_OFF);

    prep_all<<<55, 256, 0, stream>>>(p, l, hemi, V, indices, pointindex,
                                     COL, OPA, ws, emptyMask, out);
    diffuse_main<<<NPS, 256, 0, stream>>>(ws, emptyMask, out);
}